// Round 1
// baseline (115.060 us; speedup 1.0000x reference)
//
#include <hip/hip_runtime.h>

// LogSparseAttention: B=2, L=S=2048, H=8, E=D=64, fp32.
// Mask structure (win_len=sub_len=2048, log_l=11):
//   l < 22  : causal prefix 0..l
//   l >= 22 : {l-10..l} U {l-10-2^j >= 0, j=0..10}   (<= 22 columns total)
// One 64-lane wave per (b,l,h) row; lane = E/D element index.

constexpr int B = 2, L = 2048, S = 2048, H = 8, E = 64;
constexpr int LOGL = 11;
constexpr int MAXC = 2 * LOGL;          // 22
constexpr int ROWS = B * L * H;          // 32768
constexpr int WPB  = 4;                  // waves per block

__global__ __launch_bounds__(WPB * 64)
void logsparse_attn(const float* __restrict__ Q,
                    const float* __restrict__ K,
                    const float* __restrict__ V,
                    float* __restrict__ O) {
    const int lane = threadIdx.x & 63;
    const int wave = threadIdx.x >> 6;
    const int row  = blockIdx.x * WPB + wave;   // (b*L + l)*H + h
    if (row >= ROWS) return;

    const int h  = row % H;
    const int bl = row / H;
    const int l  = bl % L;
    const int b  = bl / L;

    // Build the (padded) active-column list. Compile-time bound MAXC so
    // cols[]/p[] stay in registers (no scratch spill from runtime bounds).
    int  cols[MAXC];
    bool val[MAXC];
    if (l < 2 * LOGL) {                       // full causal prefix
#pragma unroll
        for (int i = 0; i < MAXC; ++i) {
            val[i]  = (i <= l);
            cols[i] = val[i] ? i : 0;
        }
    } else {
#pragma unroll
        for (int j = 0; j < LOGL; ++j) {      // l-10 .. l
            cols[j] = l - (LOGL - 1) + j;
            val[j]  = true;
        }
#pragma unroll
        for (int j = 0; j < LOGL; ++j) {      // l-10-2^j
            int c = l - (LOGL - 1) - (1 << j);
            val[LOGL + j]  = (c >= 0);
            cols[LOGL + j] = (c >= 0) ? c : 0;
        }
    }

    const size_t qoff    = (size_t)row * E + lane;
    const float  q       = Q[qoff];
    const size_t kvbase  = ((size_t)b * S * H + h) * (size_t)E + lane;
    const size_t cstride = (size_t)H * E;     // per-column stride in K/V

    // Scores: per-lane partial products, then batched butterfly reductions
    // (loop order gives ILP across the 22 independent reductions).
    float p[MAXC];
#pragma unroll
    for (int i = 0; i < MAXC; ++i)
        p[i] = q * K[kvbase + (size_t)cols[i] * cstride];

#pragma unroll
    for (int off = 32; off; off >>= 1) {
#pragma unroll
        for (int i = 0; i < MAXC; ++i)
            p[i] += __shfl_xor(p[i], off, 64);
    }

    // Softmax over valid columns (masked -> -inf -> exp 0, matching the
    // reference's -1e9 * scale underflow).
    const float scale = 0.125f;               // 1/sqrt(64)
    float m = -1e30f;
#pragma unroll
    for (int i = 0; i < MAXC; ++i) {
        p[i] = val[i] ? p[i] * scale : -1e30f;
        m = fmaxf(m, p[i]);
    }
    float sum = 0.f;
#pragma unroll
    for (int i = 0; i < MAXC; ++i) {
        p[i] = __expf(p[i] - m);
        sum += p[i];
    }
    const float inv = 1.0f / sum;

    // O = sum_i w_i * V[col_i]
    float acc = 0.f;
#pragma unroll
    for (int i = 0; i < MAXC; ++i)
        acc += p[i] * V[kvbase + (size_t)cols[i] * cstride];

    O[qoff] = acc * inv;
}

extern "C" void kernel_launch(void* const* d_in, const int* in_sizes, int n_in,
                              void* d_out, int out_size, void* d_ws, size_t ws_size,
                              hipStream_t stream) {
    const float* Q = (const float*)d_in[0];
    const float* K = (const float*)d_in[1];
    const float* V = (const float*)d_in[2];
    float*       O = (float*)d_out;

    const int blocks = (ROWS + WPB - 1) / WPB;   // 8192
    logsparse_attn<<<dim3(blocks), dim3(WPB * 64), 0, stream>>>(Q, K, V, O);
}

// Round 2
// 94.633 us; speedup vs baseline: 1.2159x; 1.2159x over previous
//
#include <hip/hip_runtime.h>

// LogSparseAttention: B=2, L=S=2048, H=8, E=D=64, fp32.
// Mask structure (win_len=sub_len=2048, log_l=11):
//   l < 22  : causal prefix 0..l
//   l >= 22 : {l-10..l} U {l-10-2^j >= 0, j=0..10}   (<= 22 columns total)
// One 64-lane wave per (b,l,h) row; lane = E/D element index.
//
// R2: wave-sum via DPP adds (xor1, xor2, mirror7, mirror15 -> pure VALU) +
// ds_swizzle(xor16) + ds_bpermute(xor32). LDS-pipe ops 132 -> 44 per wave
// (the R1 bottleneck: ds_swizzle throughput on the per-CU LDS pipe).

constexpr int B = 2, L = 2048, S = 2048, H = 8, E = 64;
constexpr int LOGL = 11;
constexpr int MAXC = 2 * LOGL;           // 22
constexpr int ROWS = B * L * H;          // 32768
constexpr int WPB  = 4;                  // waves per block

template<int CTRL>
__device__ __forceinline__ float dpp_add(float x) {
    int y = __builtin_amdgcn_update_dpp(0, __float_as_int(x), CTRL, 0xF, 0xF, true);
    return x + __int_as_float(y);
}

__global__ __launch_bounds__(WPB * 64)
void logsparse_attn(const float* __restrict__ Q,
                    const float* __restrict__ K,
                    const float* __restrict__ V,
                    float* __restrict__ O) {
    const int lane = threadIdx.x & 63;
    const int wave = threadIdx.x >> 6;
    const int row  = blockIdx.x * WPB + wave;   // (b*L + l)*H + h
    if (row >= ROWS) return;

    const int h  = row % H;
    const int bl = row / H;
    const int l  = bl % L;
    const int b  = bl / L;

    // Build the (padded) active-column list; compile-time bound MAXC keeps
    // everything in registers.
    int  cols[MAXC];
    bool val[MAXC];
    if (l < 2 * LOGL) {                        // full causal prefix
#pragma unroll
        for (int i = 0; i < MAXC; ++i) {
            val[i]  = (i <= l);
            cols[i] = val[i] ? i : 0;
        }
    } else {
#pragma unroll
        for (int j = 0; j < LOGL; ++j) {       // l-10 .. l
            cols[j] = l - (LOGL - 1) + j;
            val[j]  = true;
        }
#pragma unroll
        for (int j = 0; j < LOGL; ++j) {       // l-10-2^j
            int c = l - (LOGL - 1) - (1 << j);
            val[LOGL + j]  = (c >= 0);
            cols[LOGL + j] = (c >= 0) ? c : 0;
        }
    }
    // cols[] are wave-uniform by construction: force into SGPRs so the
    // K/V addressing can use scalar base + lane offset.
#pragma unroll
    for (int i = 0; i < MAXC; ++i)
        cols[i] = __builtin_amdgcn_readfirstlane(cols[i]);

    const size_t qoff    = (size_t)row * E + lane;
    const float  q       = Q[qoff];
    const size_t kvbase  = ((size_t)b * S * H + h) * (size_t)E + lane;
    const size_t cstride = (size_t)H * E;      // per-column stride in K/V

    // Per-lane partial products (22 independent coalesced 256B loads).
    float p[MAXC];
#pragma unroll
    for (int i = 0; i < MAXC; ++i)
        p[i] = q * K[kvbase + (size_t)cols[i] * cstride];

    // Wave-wide sum, stage-major for ILP across the 22 independent chains.
    // Stages 1-4 are DPP-fused VALU adds (no LDS pipe):
#pragma unroll
    for (int i = 0; i < MAXC; ++i) p[i] = dpp_add<0xB1>(p[i]);   // quad_perm [1,0,3,2]: xor 1
#pragma unroll
    for (int i = 0; i < MAXC; ++i) p[i] = dpp_add<0x4E>(p[i]);   // quad_perm [2,3,0,1]: xor 2
#pragma unroll
    for (int i = 0; i < MAXC; ++i) p[i] = dpp_add<0x141>(p[i]);  // row_half_mirror (quads uniform -> 8-sum)
#pragma unroll
    for (int i = 0; i < MAXC; ++i) p[i] = dpp_add<0x140>(p[i]);  // row_mirror (-> 16-sum)
    // Stage 5: xor 16 within 32-lane halves (ds_swizzle BitMode).
#pragma unroll
    for (int i = 0; i < MAXC; ++i)
        p[i] += __int_as_float(__builtin_amdgcn_ds_swizzle(__float_as_int(p[i]), 0x401F));
    // Stage 6: xor 32 across halves (ds_bpermute, wave-wide).
    const int bp = ((lane ^ 32) << 2);
#pragma unroll
    for (int i = 0; i < MAXC; ++i)
        p[i] += __int_as_float(__builtin_amdgcn_ds_bpermute(bp, __float_as_int(p[i])));

    // Softmax over valid columns (masked -> -1e30 -> exp underflows to 0,
    // matching the reference's -1e9*scale).
    const float scale = 0.125f;                // 1/sqrt(64)
    float m = -1e30f;
#pragma unroll
    for (int i = 0; i < MAXC; ++i) {
        p[i] = val[i] ? p[i] * scale : -1e30f;
        m = fmaxf(m, p[i]);
    }
    float sum = 0.f;
#pragma unroll
    for (int i = 0; i < MAXC; ++i) {
        p[i] = __expf(p[i] - m);
        sum += p[i];
    }
    const float inv = 1.0f / sum;

    // O = sum_i w_i * V[col_i]
    float acc = 0.f;
#pragma unroll
    for (int i = 0; i < MAXC; ++i)
        acc += p[i] * V[kvbase + (size_t)cols[i] * cstride];

    O[qoff] = acc * inv;
}

extern "C" void kernel_launch(void* const* d_in, const int* in_sizes, int n_in,
                              void* d_out, int out_size, void* d_ws, size_t ws_size,
                              hipStream_t stream) {
    const float* Q = (const float*)d_in[0];
    const float* K = (const float*)d_in[1];
    const float* V = (const float*)d_in[2];
    float*       O = (float*)d_out;

    const int blocks = ROWS / WPB;             // 8192
    logsparse_attn<<<dim3(blocks), dim3(WPB * 64), 0, stream>>>(Q, K, V, O);
}

// Round 3
// 90.105 us; speedup vs baseline: 1.2770x; 1.0503x over previous
//
#include <hip/hip_runtime.h>

// LogSparseAttention: B=2, L=S=2048, H=8, E=D=64, fp32.
// Mask (win_len=sub_len=2048, log_l=11):
//   l < 22  : causal prefix 0..l
//   l >= 22 : {l-10..l} U {l-10-2^j >= 0, j=0..10}  (<= 22 columns)
//
// R3: 4 rows per wave (4 heads of the same (b,l) -> identical column set,
// wave-uniform -> SGPR addressing). Each row owns 16 lanes; each lane holds
// 4 elements (float4). Dot reduction is 4 pure-DPP stages within 16-lane
// rows (xor1, xor2, half-mirror, mirror) -> ZERO LDS-pipe ops. K/V loads are
// dwordx4 (1 KB/wave/instr) shared by 4 rows; softmax amortized 4x.

constexpr int B = 2, L = 2048, S = 2048, H = 8, E = 64;
constexpr int LOGL = 11;
constexpr int MAXC = 2 * LOGL;           // 22
constexpr int ROWS = B * L * H;          // 32768
constexpr int RPW  = 4;                  // rows (heads) per wave
constexpr int WPB  = 4;                  // waves per block
constexpr int WAVES = ROWS / RPW;        // 8192

template<int CTRL>
__device__ __forceinline__ float dpp_add(float x) {
    int y = __builtin_amdgcn_update_dpp(0, __float_as_int(x), CTRL, 0xF, 0xF, true);
    return x + __int_as_float(y);
}

__global__ __launch_bounds__(WPB * 64)
void logsparse_attn(const float4* __restrict__ Q4,
                    const float4* __restrict__ K4,
                    const float4* __restrict__ V4,
                    float4* __restrict__ O4) {
    const int lane = threadIdx.x & 63;
    const int wid  = blockIdx.x * WPB + (threadIdx.x >> 6);
    const int bl   = wid >> 1;              // b*L + l  (2 waves per (b,l))
    const int hg   = (wid & 1) * RPW;       // head group: 0 or 4
    const int l    = bl & (L - 1);
    const int b    = bl >> 11;              // L = 2048 = 2^11
    const int r    = lane >> 4;             // row (head) within wave: 0..3
    const int g    = lane & 15;             // float4 slot within row: 0..15
    const int h    = hg + r;

    // Active-column list — identical for all 4 rows (depends only on l).
    int  cols[MAXC];
    bool val[MAXC];
    if (l < 2 * LOGL) {                     // full causal prefix
#pragma unroll
        for (int i = 0; i < MAXC; ++i) {
            val[i]  = (i <= l);
            cols[i] = val[i] ? i : 0;
        }
    } else {
#pragma unroll
        for (int j = 0; j < LOGL; ++j) {    // l-10 .. l
            cols[j] = l - (LOGL - 1) + j;
            val[j]  = true;
        }
#pragma unroll
        for (int j = 0; j < LOGL; ++j) {    // l-10-2^j
            int c = l - (LOGL - 1) - (1 << j);
            val[LOGL + j]  = (c >= 0);
            cols[LOGL + j] = (c >= 0) ? c : 0;
        }
    }
    // Wave-uniform -> SGPRs, so K/V loads use scalar base + shared voffset.
#pragma unroll
    for (int i = 0; i < MAXC; ++i)
        cols[i] = __builtin_amdgcn_readfirstlane(cols[i]);

    // float4-unit indices.
    const int qidx   = (bl * H + h) * (E / 4) + g;          // Q/O lane slot
    const int kvlane = (b * S * H + h) * (E / 4) + g;       // per-lane base
    constexpr int CSTRIDE4 = H * (E / 4);                   // 128 float4/col

    const float4 q = Q4[qidx];

    // Partial dot products: 22 coalesced dwordx4 loads (1 KB/instr).
    float p[MAXC];
#pragma unroll
    for (int i = 0; i < MAXC; ++i) {
        const float4 k = K4[kvlane + cols[i] * CSTRIDE4];
        p[i] = fmaf(q.x, k.x, fmaf(q.y, k.y, fmaf(q.z, k.z, q.w * k.w)));
    }

    // 16-lane-row sum: 4 pure-DPP stages (no LDS pipe at all).
#pragma unroll
    for (int i = 0; i < MAXC; ++i) p[i] = dpp_add<0xB1>(p[i]);   // xor 1
#pragma unroll
    for (int i = 0; i < MAXC; ++i) p[i] = dpp_add<0x4E>(p[i]);   // xor 2
#pragma unroll
    for (int i = 0; i < MAXC; ++i) p[i] = dpp_add<0x141>(p[i]);  // half-mirror (=xor4 post-uniform)
#pragma unroll
    for (int i = 0; i < MAXC; ++i) p[i] = dpp_add<0x140>(p[i]);  // mirror      (=xor8 post-uniform)

    // Softmax (computed per lane; covers all 4 rows in one pass).
    const float scale = 0.125f;             // 1/sqrt(64)
    float m = -1e30f;
#pragma unroll
    for (int i = 0; i < MAXC; ++i) {
        p[i] = val[i] ? p[i] * scale : -1e30f;
        m = fmaxf(m, p[i]);
    }
    float sum = 0.f;
#pragma unroll
    for (int i = 0; i < MAXC; ++i) {
        p[i] = __expf(p[i] - m);
        sum += p[i];
    }
    const float inv = 1.0f / sum;

    // O = sum_i w_i * V[col_i]  (float4 accumulator per lane).
    float4 acc = make_float4(0.f, 0.f, 0.f, 0.f);
#pragma unroll
    for (int i = 0; i < MAXC; ++i) {
        const float4 v = V4[kvlane + cols[i] * CSTRIDE4];
        acc.x = fmaf(p[i], v.x, acc.x);
        acc.y = fmaf(p[i], v.y, acc.y);
        acc.z = fmaf(p[i], v.z, acc.z);
        acc.w = fmaf(p[i], v.w, acc.w);
    }

    O4[qidx] = make_float4(acc.x * inv, acc.y * inv, acc.z * inv, acc.w * inv);
}

extern "C" void kernel_launch(void* const* d_in, const int* in_sizes, int n_in,
                              void* d_out, int out_size, void* d_ws, size_t ws_size,
                              hipStream_t stream) {
    const float4* Q = (const float4*)d_in[0];
    const float4* K = (const float4*)d_in[1];
    const float4* V = (const float4*)d_in[2];
    float4*       O = (float4*)d_out;

    const int blocks = WAVES / WPB;          // 2048
    logsparse_attn<<<dim3(blocks), dim3(WPB * 64), 0, stream>>>(Q, K, V, O);
}

// Round 4
// 85.987 us; speedup vs baseline: 1.3381x; 1.0479x over previous
//
#include <hip/hip_runtime.h>

// LogSparseAttention: B=2, L=S=2048, H=8, E=D=64, fp32.
// Mask (win_len=sub_len=2048, log_l=11):
//   l < 22  : causal prefix 0..l
//   l >= 22 : {l-10..l} U {l-10-2^j >= 0, j=0..10}  (<= 22 columns)
//
// R3: 4 rows/wave (4 heads of same (b,l)), 16 lanes/row, float4/lane,
//     pure-DPP 16-lane reduction, SGPR column addressing.
// R4: XCD-aware block swizzle. Blocks dispatch round-robin over 8 XCDs, so
//     without swizzle every XCD streams the full 16.8 MB K+V working set
//     through its private 4 MB L2 (thrash -> L3 BW wall, ~28 us kernel).
//     Mapping logical = (phys&7)*(NBLK/8) + (phys>>3) gives each XCD a
//     contiguous 512-wide l-range: hot window columns (~2 MB) fit in L2.

constexpr int B = 2, L = 2048, S = 2048, H = 8, E = 64;
constexpr int LOGL = 11;
constexpr int MAXC = 2 * LOGL;           // 22
constexpr int ROWS = B * L * H;          // 32768
constexpr int RPW  = 4;                  // rows (heads) per wave
constexpr int WPB  = 4;                  // waves per block
constexpr int WAVES = ROWS / RPW;        // 8192
constexpr int NBLK  = WAVES / WPB;       // 2048

template<int CTRL>
__device__ __forceinline__ float dpp_add(float x) {
    int y = __builtin_amdgcn_update_dpp(0, __float_as_int(x), CTRL, 0xF, 0xF, true);
    return x + __int_as_float(y);
}

__global__ __launch_bounds__(WPB * 64)
void logsparse_attn(const float4* __restrict__ Q4,
                    const float4* __restrict__ K4,
                    const float4* __restrict__ V4,
                    float4* __restrict__ O4) {
    // XCD-aware swizzle: phys block i runs on XCD i%8; give XCD x the
    // contiguous logical range [x*NBLK/8, (x+1)*NBLK/8).
    const int logical = (blockIdx.x & 7) * (NBLK / 8) + (blockIdx.x >> 3);

    const int lane = threadIdx.x & 63;
    const int wid  = logical * WPB + (threadIdx.x >> 6);
    const int bl   = wid >> 1;              // b*L + l  (2 waves per (b,l))
    const int hg   = (wid & 1) * RPW;       // head group: 0 or 4
    const int l    = bl & (L - 1);
    const int b    = bl >> 11;              // L = 2048 = 2^11
    const int r    = lane >> 4;             // row (head) within wave: 0..3
    const int g    = lane & 15;             // float4 slot within row: 0..15
    const int h    = hg + r;

    // Active-column list — identical for all 4 rows (depends only on l).
    int  cols[MAXC];
    bool val[MAXC];
    if (l < 2 * LOGL) {                     // full causal prefix
#pragma unroll
        for (int i = 0; i < MAXC; ++i) {
            val[i]  = (i <= l);
            cols[i] = val[i] ? i : 0;
        }
    } else {
#pragma unroll
        for (int j = 0; j < LOGL; ++j) {    // l-10 .. l
            cols[j] = l - (LOGL - 1) + j;
            val[j]  = true;
        }
#pragma unroll
        for (int j = 0; j < LOGL; ++j) {    // l-10-2^j
            int c = l - (LOGL - 1) - (1 << j);
            val[LOGL + j]  = (c >= 0);
            cols[LOGL + j] = (c >= 0) ? c : 0;
        }
    }
    // Wave-uniform -> SGPRs, so K/V loads use scalar base + shared voffset.
#pragma unroll
    for (int i = 0; i < MAXC; ++i)
        cols[i] = __builtin_amdgcn_readfirstlane(cols[i]);

    // float4-unit indices.
    const int qidx   = (bl * H + h) * (E / 4) + g;          // Q/O lane slot
    const int kvlane = (b * S * H + h) * (E / 4) + g;       // per-lane base
    constexpr int CSTRIDE4 = H * (E / 4);                   // 128 float4/col

    const float4 q = Q4[qidx];

    // Partial dot products: 22 coalesced dwordx4 loads (1 KB/instr, whole
    // wave reads one contiguous 1 KB chunk = 4 heads x 256 B).
    float p[MAXC];
#pragma unroll
    for (int i = 0; i < MAXC; ++i) {
        const float4 k = K4[kvlane + cols[i] * CSTRIDE4];
        p[i] = fmaf(q.x, k.x, fmaf(q.y, k.y, fmaf(q.z, k.z, q.w * k.w)));
    }

    // 16-lane-row sum: 4 pure-DPP stages (no LDS pipe).
#pragma unroll
    for (int i = 0; i < MAXC; ++i) p[i] = dpp_add<0xB1>(p[i]);   // xor 1
#pragma unroll
    for (int i = 0; i < MAXC; ++i) p[i] = dpp_add<0x4E>(p[i]);   // xor 2
#pragma unroll
    for (int i = 0; i < MAXC; ++i) p[i] = dpp_add<0x141>(p[i]);  // half-mirror
#pragma unroll
    for (int i = 0; i < MAXC; ++i) p[i] = dpp_add<0x140>(p[i]);  // mirror

    // Softmax; masked -> -1e30 -> exp underflows to 0 (matches -1e9*scale).
    const float scale = 0.125f;             // 1/sqrt(64)
    float t[MAXC];
#pragma unroll
    for (int i = 0; i < MAXC; ++i)
        t[i] = val[i] ? p[i] * scale : -1e30f;

    // Tree max (depth 5, not a 22-deep serial chain).
    float mx[MAXC];
#pragma unroll
    for (int i = 0; i < MAXC; ++i) mx[i] = t[i];
#pragma unroll
    for (int s = 1; s < MAXC; s <<= 1)
#pragma unroll
        for (int i = 0; i + s < MAXC; i += 2 * s)
            mx[i] = fmaxf(mx[i], mx[i + s]);
    const float m = mx[0];

#pragma unroll
    for (int i = 0; i < MAXC; ++i)
        t[i] = __expf(t[i] - m);

    // Tree sum.
    float sm[MAXC];
#pragma unroll
    for (int i = 0; i < MAXC; ++i) sm[i] = t[i];
#pragma unroll
    for (int s = 1; s < MAXC; s <<= 1)
#pragma unroll
        for (int i = 0; i + s < MAXC; i += 2 * s)
            sm[i] += sm[i + s];
    const float inv = 1.0f / sm[0];

    // O = sum_i w_i * V[col_i]  (float4 accumulator per lane).
    float4 acc = make_float4(0.f, 0.f, 0.f, 0.f);
#pragma unroll
    for (int i = 0; i < MAXC; ++i) {
        const float4 v = V4[kvlane + cols[i] * CSTRIDE4];
        acc.x = fmaf(t[i], v.x, acc.x);
        acc.y = fmaf(t[i], v.y, acc.y);
        acc.z = fmaf(t[i], v.z, acc.z);
        acc.w = fmaf(t[i], v.w, acc.w);
    }

    O4[qidx] = make_float4(acc.x * inv, acc.y * inv, acc.z * inv, acc.w * inv);
}

extern "C" void kernel_launch(void* const* d_in, const int* in_sizes, int n_in,
                              void* d_out, int out_size, void* d_ws, size_t ws_size,
                              hipStream_t stream) {
    const float4* Q = (const float4*)d_in[0];
    const float4* K = (const float4*)d_in[1];
    const float4* V = (const float4*)d_in[2];
    float4*       O = (float4*)d_out;

    logsparse_attn<<<dim3(NBLK), dim3(WPB * 64), 0, stream>>>(Q, K, V, O);
}